// Round 1
// baseline (978.695 us; speedup 1.0000x reference)
//
#include <hip/hip_runtime.h>
#include <hip/hip_bf16.h>
#include <math.h>

typedef __attribute__((ext_vector_type(8))) short bf16x8;
typedef __attribute__((ext_vector_type(4))) float f32x4;
typedef __attribute__((ext_vector_type(4))) unsigned short u16x4;

constexpr int DIM  = 2048;   // K (input dim)
constexpr int NOUT = 2048;   // N (output dim)
constexpr int NH   = 32;     // heads
constexpr int TLEN = 4096;   // tokens per batch
constexpr int BM = 128, BN = 128, BK = 32;
constexpr int TILES_N = NOUT / BN + 1;   // 16 dense tiles + 1 alpha tile

// LDS tile: [row][BK] bf16, 64B rows. XOR-swizzle so that a wave's 16-lane
// column-slice read (ds_read_b128 at fixed k, rows 0..15) spreads across all
// eight 16B bank slots: slot(row) = (row&1)*4 + (kslot ^ ((row>>1)&3)).
__device__ inline int swz(int row, int kbyte) {
  return row * 64 + (kbyte ^ (((row >> 1) & 3) << 4));
}

// fp32 -> (hi, lo) bf16 by truncation. v = hi + lo + O(2^-16 |v|).
// Truncation (not RN) keeps it to ~4 VALU ops/element; the lo term captures
// the hi truncation error exactly, so only lo's own truncation remains.
__device__ inline void split4(float4 v, u16x4& h, u16x4& l) {
  float f[4] = {v.x, v.y, v.z, v.w};
  u16x4 hh, ll;
#pragma unroll
  for (int j = 0; j < 4; ++j) {
    unsigned u = __builtin_bit_cast(unsigned, f[j]);
    hh[j] = (unsigned short)(u >> 16);
    float fh = __builtin_bit_cast(float, u & 0xffff0000u);
    float fl = f[j] - fh;
    ll[j] = (unsigned short)(__builtin_bit_cast(unsigned, fl) >> 16);
  }
  h = hh;
  l = ll;
}

// C[m][n] = sum_k x[m][k] * W[n][k]  (+bias)  via split-bf16 3-pass MFMA.
// tile_n == 16 is the gate tile: B-operand = Ws (32 rows), epilogue writes
// sigmoid(acc) into alpha[m][h] instead of out.
__global__ __launch_bounds__(256, 2)
void gemm_kernel(const float* __restrict__ X, const float* __restrict__ W,
                 const float* __restrict__ Wsg, const float* __restrict__ bias,
                 float* __restrict__ out, float* __restrict__ alpha) {
  __shared__ unsigned short Ah[BM * BK], Al[BM * BK], Bh[BM * BK], Bl[BM * BK];

  const int tid  = threadIdx.x;
  const int lane = tid & 63;
  const int wid  = tid >> 6;
  const int wm = wid >> 1;   // 0..1
  const int wn = wid & 1;    // 0..1
  const int tile_n = blockIdx.x % TILES_N;
  const int tile_m = blockIdx.x / TILES_N;
  const bool atile = (tile_n == NOUT / BN);
  const size_t mbase = (size_t)tile_m * BM;
  const int nbase = tile_n * BN;

  // staging: 256 threads cover a 128x32 fp32 tile in 4 row-iterations;
  // thread t loads float4 at (row = t>>3 (+32i), k = (t&7)*4) -> coalesced.
  const int srow = tid >> 3;   // 0..31
  const int skg  = tid & 7;    // 0..7
  const float* xptr = X + (mbase + srow) * (size_t)DIM + skg * 4;
  const float* wptr = atile ? (Wsg + (size_t)srow * DIM + skg * 4)
                            : (W + ((size_t)nbase + srow) * DIM + skg * 4);
  const size_t wstride = atile ? 0 : (size_t)32 * DIM;   // Ws has only 32 rows

  f32x4 acc[4][4] = {};

  const int fr = lane & 15;   // fragment row/col
  const int kp = lane >> 4;   // k-part: k = kp*8 + j

  for (int k0 = 0; k0 < DIM; k0 += BK) {
#pragma unroll
    for (int i = 0; i < 4; ++i) {
      const int row = srow + 32 * i;
      float4 va = *(const float4*)(xptr + (size_t)32 * i * DIM + k0);
      float4 vb = *(const float4*)(wptr + wstride * i + k0);
      u16x4 ah, al, bh, bl;
      split4(va, ah, al);
      split4(vb, bh, bl);
      const int byt = swz(row, skg * 8);
      *(u16x4*)((char*)Ah + byt) = ah;
      *(u16x4*)((char*)Al + byt) = al;
      *(u16x4*)((char*)Bh + byt) = bh;
      *(u16x4*)((char*)Bl + byt) = bl;
    }
    __syncthreads();

    bf16x8 a_h[4], a_l[4], b_h[4], b_l[4];
#pragma unroll
    for (int mi = 0; mi < 4; ++mi) {
      const int row = wm * 64 + mi * 16 + fr;
      const int byt = swz(row, kp * 16);
      a_h[mi] = *(const bf16x8*)((const char*)Ah + byt);
      a_l[mi] = *(const bf16x8*)((const char*)Al + byt);
    }
#pragma unroll
    for (int ni = 0; ni < 4; ++ni) {
      const int row = wn * 64 + ni * 16 + fr;
      const int byt = swz(row, kp * 16);
      b_h[ni] = *(const bf16x8*)((const char*)Bh + byt);
      b_l[ni] = *(const bf16x8*)((const char*)Bl + byt);
    }
#pragma unroll
    for (int mi = 0; mi < 4; ++mi)
#pragma unroll
      for (int ni = 0; ni < 4; ++ni) {
        acc[mi][ni] = __builtin_amdgcn_mfma_f32_16x16x32_bf16(a_h[mi], b_h[ni], acc[mi][ni], 0, 0, 0);
        acc[mi][ni] = __builtin_amdgcn_mfma_f32_16x16x32_bf16(a_h[mi], b_l[ni], acc[mi][ni], 0, 0, 0);
        acc[mi][ni] = __builtin_amdgcn_mfma_f32_16x16x32_bf16(a_l[mi], b_h[ni], acc[mi][ni], 0, 0, 0);
      }
    __syncthreads();
  }

  // C/D layout (16x16x32): col = lane&15, row = (lane>>4)*4 + reg  [m89/m91]
  const int orow = (lane >> 4) * 4;
  const int ocol = lane & 15;
  if (!atile) {
#pragma unroll
    for (int mi = 0; mi < 4; ++mi) {
#pragma unroll
      for (int ni = 0; ni < 4; ++ni) {
        const size_t m = mbase + wm * 64 + mi * 16 + orow;
        const int n = nbase + wn * 64 + ni * 16 + ocol;
        const float bn = bias[n];
        float* po = out + m * NOUT + n;
#pragma unroll
        for (int r = 0; r < 4; ++r) po[(size_t)r * NOUT] = acc[mi][ni][r] + bn;
      }
    }
  } else {
#pragma unroll
    for (int mi = 0; mi < 4; ++mi) {
#pragma unroll
      for (int ni = 0; ni < 4; ++ni) {
        const int c = wn * 64 + ni * 16 + ocol;   // head index; uniform <32 test
        if (c < NH) {
          const size_t m = mbase + wm * 64 + mi * 16 + orow;
          float* pa = alpha + m * NH + c;
#pragma unroll
          for (int r = 0; r < 4; ++r) {
            float v = acc[mi][ni][r];
            pa[(size_t)r * NH] = 1.0f / (1.0f + expf(-v));
          }
        }
      }
    }
  }
}

// result[t] = a*out[t-1] + (1-a)*out[t], per head; t==0 -> prev = 0.
__global__ __launch_bounds__(256)
void gate_kernel(const float* __restrict__ out, const float* __restrict__ alpha,
                 float* __restrict__ res, int total4) {
  const int i = blockIdx.x * 256 + threadIdx.x;   // float4 index
  if (i >= total4) return;
  const int col4 = i & 511;        // NOUT/4 = 512 float4 per row
  const int bt   = i >> 9;
  const int h    = col4 >> 4;      // 64/4 = 16 float4 per head
  const float a  = alpha[(size_t)bt * NH + h];
  const float4 cur = ((const float4*)out)[i];
  float4 prev = {0.f, 0.f, 0.f, 0.f};
  if ((bt & (TLEN - 1)) != 0) prev = ((const float4*)out)[i - 512];
  float4 r;
  r.x = a * prev.x + (1.f - a) * cur.x;
  r.y = a * prev.y + (1.f - a) * cur.y;
  r.z = a * prev.z + (1.f - a) * cur.z;
  r.w = a * prev.w + (1.f - a) * cur.w;
  ((float4*)res)[i] = r;
}

extern "C" void kernel_launch(void* const* d_in, const int* in_sizes, int n_in,
                              void* d_out, int out_size, void* d_ws, size_t ws_size,
                              hipStream_t stream) {
  const float* x   = (const float*)d_in[0];
  const float* W   = (const float*)d_in[1];
  const float* b   = (const float*)d_in[2];
  const float* Wsg = (const float*)d_in[3];
  float* res = (float*)d_out;
  const int M = in_sizes[0] / DIM;              // B*T = 16384

  float* out_ws   = (float*)d_ws;               // M*NOUT fp32 (134 MB)
  float* alpha_ws = out_ws + (size_t)M * NOUT;  // M*NH fp32 (2 MB)

  const int blocks = (M / BM) * TILES_N;        // 128 * 17 = 2176
  gemm_kernel<<<blocks, 256, 0, stream>>>(x, W, Wsg, b, out_ws, alpha_ws);

  const int total4 = M * (NOUT / 4);
  gate_kernel<<<(total4 + 255) / 256, 256, 0, stream>>>(out_ws, alpha_ws, res, total4);
}

// Round 2
// 753.076 us; speedup vs baseline: 1.2996x; 1.2996x over previous
//
#include <hip/hip_runtime.h>
#include <hip/hip_bf16.h>
#include <math.h>

typedef __attribute__((ext_vector_type(8))) short bf16x8;
typedef __attribute__((ext_vector_type(4))) float f32x4;
typedef __attribute__((ext_vector_type(4))) unsigned short u16x4;
typedef __attribute__((ext_vector_type(8))) unsigned short u16x8;
typedef unsigned short u16;

constexpr int DIM  = 2048;   // K
constexpr int NOUT = 2048;   // N
constexpr int NH   = 32;
constexpr int TLEN = 4096;

// round-to-nearest-even fp32 -> bf16 (avoids truncation bias seen in round 1)
__device__ inline unsigned short bf16rn(float f) {
  unsigned u = __builtin_bit_cast(unsigned, f);
  u = u + 0x7fffu + ((u >> 16) & 1u);
  return (unsigned short)(u >> 16);
}

// ---------------- pre-split: fp32 [RT*128][2048] -> packed [rt*64+kt][2][128][32] bf16
__global__ __launch_bounds__(256)
void split_kernel(const float* __restrict__ in, u16* __restrict__ outp) {
  const int b  = blockIdx.x;
  const int rt = b >> 6;
  const int kt = b & 63;
  const int t  = threadIdx.x;
  const int row = t >> 1;
  const int c16 = (t & 1) << 4;
  const float* src = in + ((size_t)rt * 128 + row) * DIM + kt * 32 + c16;
  u16x8 h0, h1, l0, l1;
#pragma unroll
  for (int q = 0; q < 2; ++q) {
    float4 v0 = ((const float4*)src)[q * 2];
    float4 v1 = ((const float4*)src)[q * 2 + 1];
    float f[8] = {v0.x, v0.y, v0.z, v0.w, v1.x, v1.y, v1.z, v1.w};
    u16x8 hh, ll;
#pragma unroll
    for (int j = 0; j < 8; ++j) {
      unsigned short hb = bf16rn(f[j]);
      float fh = __builtin_bit_cast(float, (unsigned)hb << 16);
      hh[j] = hb;
      ll[j] = bf16rn(f[j] - fh);
    }
    if (q == 0) { h0 = hh; l0 = ll; } else { h1 = hh; l1 = ll; }
  }
  u16* dh = outp + ((size_t)rt * 64 + kt) * 8192 + row * 32 + c16;
  *(u16x8*)dh = h0;
  *(u16x8*)(dh + 8) = h1;
  *(u16x8*)(dh + 4096) = l0;
  *(u16x8*)(dh + 4096 + 8) = l1;
}

// async global->LDS, 16B per lane (linear: LDS dest = wave base + lane*16)
__device__ inline void gl16(const u16* g, u16* l) {
  __builtin_amdgcn_global_load_lds((const __attribute__((address_space(1))) unsigned int*)g,
                                   (__attribute__((address_space(3))) unsigned int*)l,
                                   16, 0, 0);
}

__device__ inline void split8(const float* p, bf16x8& h, bf16x8& l) {
  float4 v0 = *(const float4*)p;
  float4 v1 = *(const float4*)(p + 4);
  float f[8] = {v0.x, v0.y, v0.z, v0.w, v1.x, v1.y, v1.z, v1.w};
  bf16x8 hh, ll;
#pragma unroll
  for (int j = 0; j < 8; ++j) {
    unsigned short hb = bf16rn(f[j]);
    float fh = __builtin_bit_cast(float, (unsigned)hb << 16);
    hh[j] = (short)hb;
    ll[j] = (short)bf16rn(f[j] - fh);
  }
  h = hh; l = ll;
}

// ---------------- alpha = sigmoid(x @ Ws^T), 3-pass split-bf16 MFMA. 64 rows/block.
__global__ __launch_bounds__(256)
void alpha_kernel(const u16* __restrict__ Xp, const float* __restrict__ Wsrc,
                  float* __restrict__ alpha) {
  const int tid = threadIdx.x, lane = tid & 63, w = tid >> 6;
  const int fr = lane & 15, kp = lane >> 4;
  const int blk = blockIdx.x;
  const int mt = blk >> 1;
  const int rowoff = (blk & 1) * 64 + w * 16 + fr;
  f32x4 acc[2] = {};
  for (int kt = 0; kt < 64; ++kt) {
    const size_t pb = ((size_t)(mt * 64 + kt)) * 8192;
    bf16x8 ah = *(const bf16x8*)&Xp[pb + rowoff * 32 + kp * 8];
    bf16x8 al = *(const bf16x8*)&Xp[pb + 4096 + rowoff * 32 + kp * 8];
#pragma unroll
    for (int n = 0; n < 2; ++n) {
      bf16x8 bh, bl;
      split8(Wsrc + (size_t)(n * 16 + fr) * DIM + kt * 32 + kp * 8, bh, bl);
      acc[n] = __builtin_amdgcn_mfma_f32_16x16x32_bf16(ah, bh, acc[n], 0, 0, 0);
      acc[n] = __builtin_amdgcn_mfma_f32_16x16x32_bf16(ah, bl, acc[n], 0, 0, 0);
      acc[n] = __builtin_amdgcn_mfma_f32_16x16x32_bf16(al, bh, acc[n], 0, 0, 0);
    }
  }
  const int orow = (lane >> 4) * 4, ocol = lane & 15;
  const size_t mrow = (size_t)blk * 64 + w * 16;
#pragma unroll
  for (int n = 0; n < 2; ++n)
#pragma unroll
    for (int r = 0; r < 4; ++r) {
      float v = acc[n][r];
      alpha[(mrow + orow + r) * NH + n * 16 + ocol] = 1.0f / (1.0f + expf(-v));
    }
}

// ---------------- main GEMM (3-pass split-bf16) with fused token-shift blend epilogue
__global__ __launch_bounds__(256, 3)
void gemm_fused_kernel(const u16* __restrict__ Xp, const u16* __restrict__ Wp,
                       const float* __restrict__ bias, const float* __restrict__ alpha,
                       float* __restrict__ outp, float* __restrict__ side) {
  __shared__ u16 sAB[16384];   // A hi/lo: [0,8192) elems; B hi/lo: [8192,16384)
  const int tid = threadIdx.x;
  const int lane = tid & 63;
  const int wid = tid >> 6;
  const int wm = wid >> 1, wn = wid & 1;
  // XCD-aware swizzle: 2048 blocks, 8 XCDs, 256/XCD -> contiguous mt range per XCD
  const int sbid = (blockIdx.x & 7) * 256 + (blockIdx.x >> 3);
  const int nt = sbid & 15;
  const int mt = sbid >> 4;

  const u16* Ab = Xp + (size_t)mt * 64 * 8192 + tid * 8;
  const u16* Bb = Wp + (size_t)nt * 64 * 8192 + tid * 8;
  u16* lA = &sAB[tid * 8];
  u16* lB = &sAB[8192 + tid * 8];

  f32x4 acc[4][4] = {};
  const int fr = lane & 15, kp = lane >> 4;

  for (int kt = 0; kt < 64; ++kt) {
    const u16* ga = Ab + (size_t)kt * 8192;
    const u16* gb = Bb + (size_t)kt * 8192;
#pragma unroll
    for (int i = 0; i < 4; ++i) {
      gl16(ga + i * 2048, lA + i * 2048);
      gl16(gb + i * 2048, lB + i * 2048);
    }
    __syncthreads();
    bf16x8 bh[4], bl[4];
#pragma unroll
    for (int ni = 0; ni < 4; ++ni) {
      const int e = 8192 + (wn * 64 + ni * 16 + fr) * 32 + kp * 8;
      bh[ni] = *(const bf16x8*)&sAB[e];
      bl[ni] = *(const bf16x8*)&sAB[e + 4096];
    }
#pragma unroll
    for (int mi = 0; mi < 4; ++mi) {
      const int e = (wm * 64 + mi * 16 + fr) * 32 + kp * 8;
      bf16x8 ah = *(const bf16x8*)&sAB[e];
      bf16x8 al = *(const bf16x8*)&sAB[e + 4096];
#pragma unroll
      for (int ni = 0; ni < 4; ++ni) {
        acc[mi][ni] = __builtin_amdgcn_mfma_f32_16x16x32_bf16(ah, bh[ni], acc[mi][ni], 0, 0, 0);
        acc[mi][ni] = __builtin_amdgcn_mfma_f32_16x16x32_bf16(ah, bl[ni], acc[mi][ni], 0, 0, 0);
        acc[mi][ni] = __builtin_amdgcn_mfma_f32_16x16x32_bf16(al, bh[ni], acc[mi][ni], 0, 0, 0);
      }
    }
    __syncthreads();
  }

  // Epilogue: per 64-col chunk (== one head), round-trip through LDS so each
  // thread can read row-1 (token shift). C/D layout: col=lane&15, row=(lane>>4)*4+r.
  float* Cb = (float*)sAB;   // 128 x 64 fp32 = 32 KB (exactly the staging LDS)
  const size_t mbase = (size_t)mt * 128;
  const int ntb = nt * 128;
  const int orow = (lane >> 4) * 4;
  const int ocol = lane & 15;
  for (int c = 0; c < 2; ++c) {
    __syncthreads();
    if (wn == c) {
#pragma unroll
      for (int mi = 0; mi < 4; ++mi)
#pragma unroll
        for (int ni = 0; ni < 4; ++ni) {
          float* p = Cb + (wm * 64 + mi * 16 + orow) * 64 + ni * 16 + ocol;
#pragma unroll
          for (int r = 0; r < 4; ++r) p[r * 64] = acc[mi][ni][r];
        }
    }
    __syncthreads();
    const int head = nt * 2 + c;
    const int col = lane;
    const float bb = bias[ntb + c * 64 + col];
    for (int jj = 0; jj < 32; ++jj) {
      const int row = jj * 4 + wid;                  // wave-uniform row
      const float a = alpha[(mbase + row) * NH + head];
      const float cur = Cb[row * 64 + col];
      float r2;
      if (row == 0) r2 = (1.0f - a) * (cur + bb);                            // prev via fixup
      else          r2 = a * Cb[(row - 1) * 64 + col] + (1.0f - a) * cur + bb;
      outp[(mbase + row) * NOUT + ntb + c * 64 + col] = r2;
      if (row == 127) side[(size_t)mt * NOUT + ntb + c * 64 + col] = cur + bb;
    }
  }
}

// add a * prev(last row of previous tile) to the first row of each tile
__global__ __launch_bounds__(256)
void fixup_kernel(const float* __restrict__ alpha, const float* __restrict__ side,
                  float* __restrict__ outp) {
  const int tm = blockIdx.x + 1;
  if ((tm & 31) == 0) return;                        // batch start: prev = 0
  const int col = blockIdx.y * 256 + threadIdx.x;
  const size_t m = (size_t)tm * 128;
  const float a = alpha[m * NH + (col >> 6)];
  outp[m * NOUT + col] += a * side[(size_t)(tm - 1) * NOUT + col];
}

// ==================== fallback path (round-1, proven, 136 MB ws) ====================
__device__ inline int swz_fb(int row, int kbyte) {
  return row * 64 + (kbyte ^ (((row >> 1) & 3) << 4));
}
__device__ inline void split4_fb(float4 v, u16x4& h, u16x4& l) {
  float f[4] = {v.x, v.y, v.z, v.w};
  u16x4 hh, ll;
#pragma unroll
  for (int j = 0; j < 4; ++j) {
    unsigned u = __builtin_bit_cast(unsigned, f[j]);
    hh[j] = (unsigned short)(u >> 16);
    float fh = __builtin_bit_cast(float, u & 0xffff0000u);
    ll[j] = (unsigned short)(__builtin_bit_cast(unsigned, f[j] - fh) >> 16);
  }
  h = hh; l = ll;
}
__global__ __launch_bounds__(256, 2)
void gemm_fb(const float* __restrict__ X, const float* __restrict__ W,
             const float* __restrict__ Wsg, const float* __restrict__ bias,
             float* __restrict__ out, float* __restrict__ alpha) {
  __shared__ unsigned short Ah[128 * 32], Al[128 * 32], Bh[128 * 32], Bl[128 * 32];
  const int tid = threadIdx.x, lane = tid & 63, wid = tid >> 6;
  const int wm = wid >> 1, wn = wid & 1;
  const int tile_n = blockIdx.x % 17, tile_m = blockIdx.x / 17;
  const bool atile = (tile_n == 16);
  const size_t mbase = (size_t)tile_m * 128;
  const int nbase = tile_n * 128;
  const int srow = tid >> 3, skg = tid & 7;
  const float* xptr = X + (mbase + srow) * (size_t)DIM + skg * 4;
  const float* wptr = atile ? (Wsg + (size_t)srow * DIM + skg * 4)
                            : (W + ((size_t)nbase + srow) * DIM + skg * 4);
  const size_t wstride = atile ? 0 : (size_t)32 * DIM;
  f32x4 acc[4][4] = {};
  const int fr = lane & 15, kp = lane >> 4;
  for (int k0 = 0; k0 < DIM; k0 += 32) {
#pragma unroll
    for (int i = 0; i < 4; ++i) {
      float4 va = *(const float4*)(xptr + (size_t)32 * i * DIM + k0);
      float4 vb = *(const float4*)(wptr + wstride * i + k0);
      u16x4 ah, al, bh, bl;
      split4_fb(va, ah, al);
      split4_fb(vb, bh, bl);
      const int byt = swz_fb(srow + 32 * i, skg * 8);
      *(u16x4*)((char*)Ah + byt) = ah; *(u16x4*)((char*)Al + byt) = al;
      *(u16x4*)((char*)Bh + byt) = bh; *(u16x4*)((char*)Bl + byt) = bl;
    }
    __syncthreads();
    bf16x8 a_h[4], a_l[4], b_h[4], b_l[4];
#pragma unroll
    for (int mi = 0; mi < 4; ++mi) {
      const int byt = swz_fb(wm * 64 + mi * 16 + fr, kp * 16);
      a_h[mi] = *(const bf16x8*)((const char*)Ah + byt);
      a_l[mi] = *(const bf16x8*)((const char*)Al + byt);
    }
#pragma unroll
    for (int ni = 0; ni < 4; ++ni) {
      const int byt = swz_fb(wn * 64 + ni * 16 + fr, kp * 16);
      b_h[ni] = *(const bf16x8*)((const char*)Bh + byt);
      b_l[ni] = *(const bf16x8*)((const char*)Bl + byt);
    }
#pragma unroll
    for (int mi = 0; mi < 4; ++mi)
#pragma unroll
      for (int ni = 0; ni < 4; ++ni) {
        acc[mi][ni] = __builtin_amdgcn_mfma_f32_16x16x32_bf16(a_h[mi], b_h[ni], acc[mi][ni], 0, 0, 0);
        acc[mi][ni] = __builtin_amdgcn_mfma_f32_16x16x32_bf16(a_h[mi], b_l[ni], acc[mi][ni], 0, 0, 0);
        acc[mi][ni] = __builtin_amdgcn_mfma_f32_16x16x32_bf16(a_l[mi], b_h[ni], acc[mi][ni], 0, 0, 0);
      }
    __syncthreads();
  }
  const int orow = (lane >> 4) * 4, ocol = lane & 15;
  if (!atile) {
#pragma unroll
    for (int mi = 0; mi < 4; ++mi)
#pragma unroll
      for (int ni = 0; ni < 4; ++ni) {
        const size_t m = mbase + wm * 64 + mi * 16 + orow;
        const int n = nbase + wn * 64 + ni * 16 + ocol;
        const float bn = bias[n];
        float* po = out + m * NOUT + n;
#pragma unroll
        for (int r = 0; r < 4; ++r) po[(size_t)r * NOUT] = acc[mi][ni][r] + bn;
      }
  } else {
#pragma unroll
    for (int mi = 0; mi < 4; ++mi)
#pragma unroll
      for (int ni = 0; ni < 4; ++ni) {
        const int c = wn * 64 + ni * 16 + ocol;
        if (c < NH) {
          const size_t m = mbase + wm * 64 + mi * 16 + orow;
#pragma unroll
          for (int r = 0; r < 4; ++r)
            alpha[(m + r) * NH + c] = 1.0f / (1.0f + expf(-acc[mi][ni][r]));
        }
      }
  }
}
__global__ __launch_bounds__(256)
void gate_fb(const float* __restrict__ out, const float* __restrict__ alpha,
             float* __restrict__ res, int total4) {
  const int i = blockIdx.x * 256 + threadIdx.x;
  if (i >= total4) return;
  const int bt = i >> 9, h = (i & 511) >> 4;
  const float a = alpha[(size_t)bt * NH + h];
  const float4 cur = ((const float4*)out)[i];
  float4 prev = {0.f, 0.f, 0.f, 0.f};
  if ((bt & (TLEN - 1)) != 0) prev = ((const float4*)out)[i - 512];
  float4 r;
  r.x = a * prev.x + (1.f - a) * cur.x; r.y = a * prev.y + (1.f - a) * cur.y;
  r.z = a * prev.z + (1.f - a) * cur.z; r.w = a * prev.w + (1.f - a) * cur.w;
  ((float4*)res)[i] = r;
}
// ====================================================================================

extern "C" void kernel_launch(void* const* d_in, const int* in_sizes, int n_in,
                              void* d_out, int out_size, void* d_ws, size_t ws_size,
                              hipStream_t stream) {
  const float* x   = (const float*)d_in[0];
  const float* W   = (const float*)d_in[1];
  const float* b   = (const float*)d_in[2];
  const float* Wsg = (const float*)d_in[3];
  float* res = (float*)d_out;
  const int M = in_sizes[0] / DIM;                        // 16384

  const size_t xp_bytes = (size_t)2 * M * DIM * 2;        // 134,217,728
  const size_t wp_bytes = (size_t)2 * NOUT * DIM * 2;     //  16,777,216
  const size_t al_bytes = (size_t)M * NH * 4;             //   2,097,152
  const size_t sd_bytes = (size_t)(M / 128) * NOUT * 4;   //   1,048,576
  const size_t need = xp_bytes + wp_bytes + al_bytes + sd_bytes;

  if (ws_size >= need) {
    u16* Xp      = (u16*)d_ws;
    u16* Wp      = (u16*)((char*)d_ws + xp_bytes);
    float* alpha = (float*)((char*)d_ws + xp_bytes + wp_bytes);
    float* side  = (float*)((char*)d_ws + xp_bytes + wp_bytes + al_bytes);

    split_kernel<<<(M / 128) * 64, 256, 0, stream>>>(x, Xp);
    split_kernel<<<(NOUT / 128) * 64, 256, 0, stream>>>(W, Wp);
    alpha_kernel<<<M / 64, 256, 0, stream>>>(Xp, Wsg, alpha);
    gemm_fused_kernel<<<(M / 128) * 16, 256, 0, stream>>>(Xp, Wp, b, alpha, res, side);
    fixup_kernel<<<dim3(M / 128 - 1, 8), 256, 0, stream>>>(alpha, side, res);
  } else {
    float* out_ws   = (float*)d_ws;
    float* alpha_ws = out_ws + (size_t)M * NOUT;
    gemm_fb<<<(M / 128) * 17, 256, 0, stream>>>(x, W, Wsg, b, out_ws, alpha_ws);
    const int total4 = M * (NOUT / 4);
    gate_fb<<<(total4 + 255) / 256, 256, 0, stream>>>(out_ws, alpha_ws, res, total4);
  }
}